// Round 8
// baseline (73.966 us; speedup 1.0000x reference)
//
#include <hip/hip_runtime.h>

// Problem: B=16,H=16,P=128,D=128,NF=12
// rows per branch = B*H*P = 32768; total rows (q then k) = 65536.
//
// R8 structure: zero-LDS, zero-barrier k_branch with column-split waves.
//   Work = 65536 rows / 16 rows-per-wave = 4096 waves = only 16 waves/CU (50%
//   occupancy hard cap) -> split each wave's tile in half column-wise:
//   8192 waves of 16 rows x 64 cols. No LDS, no barriers:
//     - A-frags: silu(x) computed in-register per k-step (transient)
//     - B-frags: read from wbf (32 KB, L1/L2-resident) per k-step
//     - epilogue in C-fragment layout, coef hoisted per n-tile
//   Col-halves write disjoint sums_lo / sums_hi; consumers add them.
//
// ws layout (floats):
//   sums_lo: [0, 65536)        sums_hi: [65536, 131072)
//   R:       [131072, 131200)  T:       [131200, 163968)
//   wbf:     ushort[16384] at float offset 163968

typedef float          f32x4 __attribute__((ext_vector_type(4)));
typedef short          s16x8 __attribute__((ext_vector_type(8)));

static __device__ __forceinline__ unsigned short f2bf(float f) {
    unsigned int u = __float_as_uint(f);
    u += 0x7FFFu + ((u >> 16) & 1u);       // round-to-nearest-even
    return (unsigned short)(u >> 16);
}

__global__ __launch_bounds__(256) void k_convert(const float* __restrict__ bw,
                                                 unsigned short* __restrict__ wbf) {
    int i = blockIdx.x * 256 + threadIdx.x;
    if (i < 128 * 128) wbf[i] = f2bf(bw[i]);
}

// 512 threads = 8 waves; block owns 64 rows; wave (wr,ch): rows wr*16..+15,
// cols ch*64..+63. Grid 1024.
__global__ __launch_bounds__(512, 5) void k_branch(
    const float* __restrict__ q, const float* __restrict__ k,
    const unsigned short* __restrict__ wbf,   // base_weight bf16 [d][e] (= B[n][k])
    const float* __restrict__ gridv,          // [12], == 1..12
    const float* __restrict__ coef_q, const float* __restrict__ coef_k,
    const float* __restrict__ sbase,          // scale_base (1,H,P,D)
    const float* __restrict__ ssp,            // scale_sp   (1,H,P,D)
    float* __restrict__ sums_lo, float* __restrict__ sums_hi)
{
    const int t = threadIdx.x;
    const int lane = t & 63;
    const int w = t >> 6;                     // 0..7
    const int wr = w >> 1;                    // row group 0..3
    const int ch = w & 1;                     // col half 0/1
    const int r15 = lane & 15, g4 = lane >> 4;
    const int row0 = blockIdx.x * 64;
    const bool is_q = row0 < 32768;
    const float* X = is_q ? q : k;
    const float* coef = is_q ? coef_q : coef_k;
    const int xrow0 = is_q ? row0 : row0 - 32768;
    const float g1 = gridv[0];                // == 1.0; freqs are g1*(1..12)

    // ---- MFMA with in-register A-frags (silu) and global B-frags ----
    const float* xrowp = &X[(xrow0 + wr * 16 + r15) * 128];

    f32x4 acc[4];
    #pragma unroll
    for (int n = 0; n < 4; ++n) acc[n] = (f32x4){0.f, 0.f, 0.f, 0.f};

    #pragma unroll
    for (int s = 0; s < 4; ++s) {
        // A-frag: lane (r15,g4) holds silu(x[row=wr*16+r15][k=s*32+g4*8 ..+7])
        const float4* xp = (const float4*)&xrowp[s * 32 + g4 * 8];
        float4 x0 = xp[0], x1 = xp[1];
        float xs[8] = {x0.x, x0.y, x0.z, x0.w, x1.x, x1.y, x1.z, x1.w};
        s16x8 af;
        #pragma unroll
        for (int j = 0; j < 8; ++j) {
            float s1 = xs[j] / (1.f + __expf(-xs[j]));
            af[j] = (short)f2bf(s1);
        }
        #pragma unroll
        for (int n = 0; n < 4; ++n) {
            // B-frag: row(d)=ch*64+n*16+r15, k=s*32+g4*8 (L1-resident)
            s16x8 bf = *(const s16x8*)&wbf[(ch * 64 + n * 16 + r15) * 128
                                           + s * 32 + g4 * 8];
            acc[n] = __builtin_amdgcn_mfma_f32_16x16x32_bf16(af, bf, acc[n], 0, 0, 0);
        }
    }

    // ---- epilogue in C-frag layout: col=ch*64+n*16+r15, row=g4*4+reg ----
    float psum[4] = {0.f, 0.f, 0.f, 0.f};
    #pragma unroll
    for (int n = 0; n < 4; ++n) {
        int col = ch * 64 + n * 16 + r15;
        const float4* cp = (const float4*)&coef[col * 12];
        float4 c0 = cp[0], c1 = cp[1], c2 = cp[2];
        float cf[12] = {c0.x, c0.y, c0.z, c0.w, c1.x, c1.y, c1.z, c1.w,
                        c2.x, c2.y, c2.z, c2.w};
        #pragma unroll
        for (int reg = 0; reg < 4; ++reg) {
            int rib = wr * 16 + g4 * 4 + reg;       // row in block
            int hp = (row0 + rib) & 2047;           // h*128+p (scales bcast over B)
            float xv  = X[(xrow0 + rib) * 128 + col];   // L1 hit
            float spv = ssp[hp * 128 + col];
            float sbv = sbase[hp * 128 + col];
            float a = g1 * xv;
            float s1 = __sinf(a);                   // native v_sin_f32
            float cv = __cosf(a);                   // native v_cos_f32
            float t2 = cv + cv;
            float sprev = 0.f, scur = s1;
            float f = cf[0] * s1;
            #pragma unroll
            for (int u = 1; u < 12; ++u) {
                float snext = __builtin_fmaf(t2, scur, -sprev);
                f = __builtin_fmaf(cf[u], snext, f);
                sprev = scur; scur = snext;
            }
            float z = f * spv + acc[n][reg] * sbv;
            psum[reg] += 1.f / (1.f + __expf(-z));
        }
    }
    // reduce partial row-sums over the 16 r15 lanes; write this col-half
    float* dst = ch ? sums_hi : sums_lo;
    #pragma unroll
    for (int reg = 0; reg < 4; ++reg) {
        float v = psum[reg];
        v += __shfl_xor(v, 1, 64);
        v += __shfl_xor(v, 2, 64);
        v += __shfl_xor(v, 4, 64);
        v += __shfl_xor(v, 8, 64);
        if (r15 == 0) dst[row0 + wr * 16 + g4 * 4 + reg] = v;
    }
}

// T[bh][j] = sum_p sk[bh][p]*w_qk[j][p] + b_qk[j]; block 256 computes R[j].
__global__ __launch_bounds__(128) void k_tvec(
    const float* __restrict__ sums_lo, const float* __restrict__ sums_hi,
    const float* __restrict__ w_qk, const float* __restrict__ b_qk,
    float* __restrict__ T, float* __restrict__ R)
{
    __shared__ float skl[128];
    int bh = blockIdx.x;
    int t = threadIdx.x;
    const float4* wr = (const float4*)&w_qk[t * 128];
    if (bh < 256) {
        int idx = 32768 + bh * 128 + t;
        skl[t] = sums_lo[idx] + sums_hi[idx];
        __syncthreads();
        float a = 0.f;
        #pragma unroll 8
        for (int p4 = 0; p4 < 32; ++p4) {
            float4 w4 = wr[p4];
            a += w4.x * skl[p4 * 4 + 0] + w4.y * skl[p4 * 4 + 1] +
                 w4.z * skl[p4 * 4 + 2] + w4.w * skl[p4 * 4 + 3];
        }
        T[bh * 128 + t] = a + b_qk[t];
    } else {
        float a = 0.f;
        #pragma unroll 8
        for (int p4 = 0; p4 < 32; ++p4) {
            float4 w4 = wr[p4];
            a += w4.x + w4.y + w4.z + w4.w;
        }
        R[t] = a;
    }
}

// Softmax over j: logit[j] = sq[row]*R[j] + T[bh][j]. One wave per row.
__global__ __launch_bounds__(256) void k_softmax(
    const float* __restrict__ sums_lo, const float* __restrict__ sums_hi,
    const float* __restrict__ T, const float* __restrict__ R,
    float* __restrict__ out)
{
    int row = blockIdx.x * 4 + (threadIdx.x >> 6);
    int lane = threadIdx.x & 63;
    int bh = row >> 7;
    float sqv = sums_lo[row] + sums_hi[row];
    float2 r2 = *(const float2*)&R[lane * 2];
    float2 t2 = *(const float2*)&T[bh * 128 + lane * 2];
    float l0 = sqv * r2.x + t2.x;
    float l1 = sqv * r2.y + t2.y;
    float m = fmaxf(l0, l1);
    #pragma unroll
    for (int s = 32; s >= 1; s >>= 1) m = fmaxf(m, __shfl_xor(m, s, 64));
    float e0 = __expf(l0 - m), e1 = __expf(l1 - m);
    float sum = e0 + e1;
    #pragma unroll
    for (int w2 = 32; w2 >= 1; w2 >>= 1) sum += __shfl_xor(sum, w2, 64);
    float inv = 1.f / sum;
    float2 o2 = {e0 * inv, e1 * inv};
    *(float2*)&out[row * 128 + lane * 2] = o2;
}

extern "C" void kernel_launch(void* const* d_in, const int* in_sizes, int n_in,
                              void* d_out, int out_size, void* d_ws, size_t ws_size,
                              hipStream_t stream) {
    (void)in_sizes; (void)n_in; (void)out_size; (void)ws_size;
    const float* q      = (const float*)d_in[0];
    const float* k      = (const float*)d_in[1];
    // d_in[2] = scale (unused by reference forward)
    const float* gridv  = (const float*)d_in[3];
    const float* bw     = (const float*)d_in[4];
    const float* coef_q = (const float*)d_in[5];
    const float* coef_k = (const float*)d_in[6];
    const float* sbase  = (const float*)d_in[7];   // scale_base
    const float* ssp    = (const float*)d_in[8];   // scale_sp
    const float* w_qk   = (const float*)d_in[9];
    const float* b_qk   = (const float*)d_in[10];

    float* out  = (float*)d_out;
    float* ws      = (float*)d_ws;
    float* sums_lo = ws;                            // 65536
    float* sums_hi = ws + 65536;                    // 65536
    float* R       = ws + 131072;                   // 128
    float* T       = ws + 131200;                   // 32768
    unsigned short* wbf = (unsigned short*)(ws + 163968);  // 16384 ushorts

    k_convert<<<64, 256, 0, stream>>>(bw, wbf);
    k_branch<<<1024, 512, 0, stream>>>(q, k, wbf, gridv, coef_q, coef_k,
                                       sbase, ssp, sums_lo, sums_hi);
    k_tvec<<<257, 128, 0, stream>>>(sums_lo, sums_hi, w_qk, b_qk, T, R);
    k_softmax<<<32768 / 4, 256, 0, stream>>>(sums_lo, sums_hi, T, R, out);
}

// Round 9
// 55.852 us; speedup vs baseline: 1.3243x; 1.3243x over previous
//
#include <hip/hip_runtime.h>

// Problem: B=16,H=16,P=128,D=128,NF=12
// rows per branch = B*H*P = 32768; total rows (q then k) = 65536.
//
// R9 = R8 structure (zero-LDS, zero-barrier, column-split waves) with the
// register budget fixed: __launch_bounds__(512,4) -> 128 unified VGPR+AGPR
// per thread. R8's (512,5) squeezed the budget to 96 (48 VGPR + 48 AGPR)
// and spilled the epilogue (WRITE_SIZE 54 MB). Nothing else changed.
//
// ws layout (floats):
//   sums_lo: [0, 65536)        sums_hi: [65536, 131072)
//   R:       [131072, 131200)  T:       [131200, 163968)
//   wbf:     ushort[16384] at float offset 163968

typedef float          f32x4 __attribute__((ext_vector_type(4)));
typedef short          s16x8 __attribute__((ext_vector_type(8)));

static __device__ __forceinline__ unsigned short f2bf(float f) {
    unsigned int u = __float_as_uint(f);
    u += 0x7FFFu + ((u >> 16) & 1u);       // round-to-nearest-even
    return (unsigned short)(u >> 16);
}

__global__ __launch_bounds__(256) void k_convert(const float* __restrict__ bw,
                                                 unsigned short* __restrict__ wbf) {
    int i = blockIdx.x * 256 + threadIdx.x;
    if (i < 128 * 128) wbf[i] = f2bf(bw[i]);
}

// 512 threads = 8 waves; block owns 64 rows; wave (wr,ch): rows wr*16..+15,
// cols ch*64..+63. Grid 1024.
__global__ __launch_bounds__(512, 4) void k_branch(
    const float* __restrict__ q, const float* __restrict__ k,
    const unsigned short* __restrict__ wbf,   // base_weight bf16 [d][e] (= B[n][k])
    const float* __restrict__ gridv,          // [12], == 1..12
    const float* __restrict__ coef_q, const float* __restrict__ coef_k,
    const float* __restrict__ sbase,          // scale_base (1,H,P,D)
    const float* __restrict__ ssp,            // scale_sp   (1,H,P,D)
    float* __restrict__ sums_lo, float* __restrict__ sums_hi)
{
    const int t = threadIdx.x;
    const int lane = t & 63;
    const int w = t >> 6;                     // 0..7
    const int wr = w >> 1;                    // row group 0..3
    const int ch = w & 1;                     // col half 0/1
    const int r15 = lane & 15, g4 = lane >> 4;
    const int row0 = blockIdx.x * 64;
    const bool is_q = row0 < 32768;
    const float* X = is_q ? q : k;
    const float* coef = is_q ? coef_q : coef_k;
    const int xrow0 = is_q ? row0 : row0 - 32768;
    const float g1 = gridv[0];                // == 1.0; freqs are g1*(1..12)

    // ---- MFMA with in-register A-frags (silu) and global B-frags ----
    const float* xrowp = &X[(xrow0 + wr * 16 + r15) * 128];

    f32x4 acc[4];
    #pragma unroll
    for (int n = 0; n < 4; ++n) acc[n] = (f32x4){0.f, 0.f, 0.f, 0.f};

    #pragma unroll
    for (int s = 0; s < 4; ++s) {
        // A-frag: lane (r15,g4) holds silu(x[row=wr*16+r15][k=s*32+g4*8 ..+7])
        const float4* xp = (const float4*)&xrowp[s * 32 + g4 * 8];
        float4 x0 = xp[0], x1 = xp[1];
        float xs[8] = {x0.x, x0.y, x0.z, x0.w, x1.x, x1.y, x1.z, x1.w};
        s16x8 af;
        #pragma unroll
        for (int j = 0; j < 8; ++j) {
            float s1 = xs[j] / (1.f + __expf(-xs[j]));
            af[j] = (short)f2bf(s1);
        }
        #pragma unroll
        for (int n = 0; n < 4; ++n) {
            // B-frag: row(d)=ch*64+n*16+r15, k=s*32+g4*8 (L1/L2-resident)
            s16x8 bf = *(const s16x8*)&wbf[(ch * 64 + n * 16 + r15) * 128
                                           + s * 32 + g4 * 8];
            acc[n] = __builtin_amdgcn_mfma_f32_16x16x32_bf16(af, bf, acc[n], 0, 0, 0);
        }
    }

    // ---- epilogue in C-frag layout: col=ch*64+n*16+r15, row=g4*4+reg ----
    float psum[4] = {0.f, 0.f, 0.f, 0.f};
    #pragma unroll
    for (int n = 0; n < 4; ++n) {
        int col = ch * 64 + n * 16 + r15;
        const float4* cp = (const float4*)&coef[col * 12];
        float4 c0 = cp[0], c1 = cp[1], c2 = cp[2];
        float cf[12] = {c0.x, c0.y, c0.z, c0.w, c1.x, c1.y, c1.z, c1.w,
                        c2.x, c2.y, c2.z, c2.w};
        #pragma unroll
        for (int reg = 0; reg < 4; ++reg) {
            int rib = wr * 16 + g4 * 4 + reg;       // row in block
            int hp = (row0 + rib) & 2047;           // h*128+p (scales bcast over B)
            float xv  = X[(xrow0 + rib) * 128 + col];   // L1 hit
            float spv = ssp[hp * 128 + col];
            float sbv = sbase[hp * 128 + col];
            float a = g1 * xv;
            float s1 = __sinf(a);                   // native v_sin_f32
            float cv = __cosf(a);                   // native v_cos_f32
            float t2 = cv + cv;
            float sprev = 0.f, scur = s1;
            float f = cf[0] * s1;
            #pragma unroll
            for (int u = 1; u < 12; ++u) {
                float snext = __builtin_fmaf(t2, scur, -sprev);
                f = __builtin_fmaf(cf[u], snext, f);
                sprev = scur; scur = snext;
            }
            float z = f * spv + acc[n][reg] * sbv;
            psum[reg] += 1.f / (1.f + __expf(-z));
        }
    }
    // reduce partial row-sums over the 16 r15 lanes; write this col-half
    float* dst = ch ? sums_hi : sums_lo;
    #pragma unroll
    for (int reg = 0; reg < 4; ++reg) {
        float v = psum[reg];
        v += __shfl_xor(v, 1, 64);
        v += __shfl_xor(v, 2, 64);
        v += __shfl_xor(v, 4, 64);
        v += __shfl_xor(v, 8, 64);
        if (r15 == 0) dst[row0 + wr * 16 + g4 * 4 + reg] = v;
    }
}

// T[bh][j] = sum_p sk[bh][p]*w_qk[j][p] + b_qk[j]; block 256 computes R[j].
__global__ __launch_bounds__(128) void k_tvec(
    const float* __restrict__ sums_lo, const float* __restrict__ sums_hi,
    const float* __restrict__ w_qk, const float* __restrict__ b_qk,
    float* __restrict__ T, float* __restrict__ R)
{
    __shared__ float skl[128];
    int bh = blockIdx.x;
    int t = threadIdx.x;
    const float4* wr = (const float4*)&w_qk[t * 128];
    if (bh < 256) {
        int idx = 32768 + bh * 128 + t;
        skl[t] = sums_lo[idx] + sums_hi[idx];
        __syncthreads();
        float a = 0.f;
        #pragma unroll 8
        for (int p4 = 0; p4 < 32; ++p4) {
            float4 w4 = wr[p4];
            a += w4.x * skl[p4 * 4 + 0] + w4.y * skl[p4 * 4 + 1] +
                 w4.z * skl[p4 * 4 + 2] + w4.w * skl[p4 * 4 + 3];
        }
        T[bh * 128 + t] = a + b_qk[t];
    } else {
        float a = 0.f;
        #pragma unroll 8
        for (int p4 = 0; p4 < 32; ++p4) {
            float4 w4 = wr[p4];
            a += w4.x + w4.y + w4.z + w4.w;
        }
        R[t] = a;
    }
}

// Softmax over j: logit[j] = sq[row]*R[j] + T[bh][j]. One wave per row.
__global__ __launch_bounds__(256) void k_softmax(
    const float* __restrict__ sums_lo, const float* __restrict__ sums_hi,
    const float* __restrict__ T, const float* __restrict__ R,
    float* __restrict__ out)
{
    int row = blockIdx.x * 4 + (threadIdx.x >> 6);
    int lane = threadIdx.x & 63;
    int bh = row >> 7;
    float sqv = sums_lo[row] + sums_hi[row];
    float2 r2 = *(const float2*)&R[lane * 2];
    float2 t2 = *(const float2*)&T[bh * 128 + lane * 2];
    float l0 = sqv * r2.x + t2.x;
    float l1 = sqv * r2.y + t2.y;
    float m = fmaxf(l0, l1);
    #pragma unroll
    for (int s = 32; s >= 1; s >>= 1) m = fmaxf(m, __shfl_xor(m, s, 64));
    float e0 = __expf(l0 - m), e1 = __expf(l1 - m);
    float sum = e0 + e1;
    #pragma unroll
    for (int w2 = 32; w2 >= 1; w2 >>= 1) sum += __shfl_xor(sum, w2, 64);
    float inv = 1.f / sum;
    float2 o2 = {e0 * inv, e1 * inv};
    *(float2*)&out[row * 128 + lane * 2] = o2;
}

extern "C" void kernel_launch(void* const* d_in, const int* in_sizes, int n_in,
                              void* d_out, int out_size, void* d_ws, size_t ws_size,
                              hipStream_t stream) {
    (void)in_sizes; (void)n_in; (void)out_size; (void)ws_size;
    const float* q      = (const float*)d_in[0];
    const float* k      = (const float*)d_in[1];
    // d_in[2] = scale (unused by reference forward)
    const float* gridv  = (const float*)d_in[3];
    const float* bw     = (const float*)d_in[4];
    const float* coef_q = (const float*)d_in[5];
    const float* coef_k = (const float*)d_in[6];
    const float* sbase  = (const float*)d_in[7];   // scale_base
    const float* ssp    = (const float*)d_in[8];   // scale_sp
    const float* w_qk   = (const float*)d_in[9];
    const float* b_qk   = (const float*)d_in[10];

    float* out  = (float*)d_out;
    float* ws      = (float*)d_ws;
    float* sums_lo = ws;                            // 65536
    float* sums_hi = ws + 65536;                    // 65536
    float* R       = ws + 131072;                   // 128
    float* T       = ws + 131200;                   // 32768
    unsigned short* wbf = (unsigned short*)(ws + 163968);  // 16384 ushorts

    k_convert<<<64, 256, 0, stream>>>(bw, wbf);
    k_branch<<<1024, 512, 0, stream>>>(q, k, wbf, gridv, coef_q, coef_k,
                                       sbase, ssp, sums_lo, sums_hi);
    k_tvec<<<257, 128, 0, stream>>>(sums_lo, sums_hi, w_qk, b_qk, T, R);
    k_softmax<<<32768 / 4, 256, 0, stream>>>(sums_lo, sums_hi, T, R, out);
}